// Round 6
// baseline (522.325 us; speedup 1.0000x reference)
//
#include <hip/hip_runtime.h>

// ---------------------------------------------------------------------------
// GCN encoder (4 conv layers, shared CSR graph) + 3-layer MLP decoder.
// Round 6: agg_kernel gathers 16 B/lane (uint4) — one VMEM instruction per
// 4 edge rows; 4 edge-groups x 16 col-positions per wave, shfl_xor fold.
// ---------------------------------------------------------------------------

typedef __attribute__((ext_vector_type(8))) short short8;
typedef __attribute__((ext_vector_type(4))) float floatx4;

#define BIN_CH 8192          // edges per bin block
#define NBMAX 512            // max buckets supported

__device__ __forceinline__ unsigned short f2bf(float f) {
    unsigned int u = __float_as_uint(f);
    u += 0x7fffu + ((u >> 16) & 1u);          // round-to-nearest-even
    return (unsigned short)(u >> 16);
}
__device__ __forceinline__ float bflo(unsigned int u) { return __uint_as_float(u << 16); }
__device__ __forceinline__ float bfhi(unsigned int u) { return __uint_as_float(u & 0xffff0000u); }

// ---- graph build ----------------------------------------------------------

// block-aggregated binning: LDS hist -> local scan -> 1 global atomic per
// (block,bucket) run reservation -> dense run writes into bucket segments.
__global__ __launch_bounds__(512) void bin_kernel(
        const int* __restrict__ src, const int* __restrict__ dst,
        int* __restrict__ gfill, unsigned int* __restrict__ binbuf,
        int NB, int C, int E) {
    __shared__ int hist[NBMAX];
    __shared__ int start[NBMAX];
    __shared__ int dstoff[NBMAX];
    int tid = threadIdx.x;
    int e0 = blockIdx.x * BIN_CH;
    for (int i = tid; i < NB; i += 512) hist[i] = 0;
    __syncthreads();
    for (int i = tid; i < BIN_CH; i += 512) {
        int e = e0 + i;
        if (e < E) atomicAdd(&hist[dst[e] >> 9], 1);
    }
    __syncthreads();
    if (tid < 64) {                       // wave 0: exclusive scan hist->start
        int carry = 0;
        for (int base = 0; base < NB; base += 64) {
            int idx = base + tid;
            int v = (idx < NB) ? hist[idx] : 0;
            int s = v;
            #pragma unroll
            for (int off = 1; off < 64; off <<= 1) {
                int u = __shfl_up(s, off);
                if (tid >= off) s += u;
            }
            if (idx < NB) start[idx] = carry + s - v;
            carry += __shfl(s, 63);
        }
    }
    __syncthreads();
    for (int i = tid; i < NB; i += 512) { // reserve global runs
        int cnt = hist[i];
        int g = cnt ? atomicAdd(&gfill[i], cnt) : 0;
        dstoff[i] = g - start[i];
        hist[i] = start[i];               // reuse as local cursor
    }
    __syncthreads();
    for (int i = tid; i < BIN_CH; i += 512) {
        int e = e0 + i;
        if (e >= E) continue;
        int d = dst[e];
        int b = d >> 9;
        int slot = atomicAdd(&hist[b], 1);            // local rank
        int gidx = b * C + dstoff[b] + slot;
        if (gidx < (b + 1) * C)
            binbuf[gidx] = (unsigned int)src[e] | ((unsigned int)(d & 511) << 17);
    }
}

// exclusive scan over NB bucket sizes (1 wave)
__global__ void bscan_kernel(const int* __restrict__ gfill, int* __restrict__ bbase, int NB) {
    int lane = threadIdx.x;
    int carry = 0;
    for (int base = 0; base < NB; base += 64) {
        int idx = base + lane;
        int v = (idx < NB) ? gfill[idx] : 0;
        int s = v;
        #pragma unroll
        for (int off = 1; off < 64; off <<= 1) {
            int u = __shfl_up(s, off);
            if (lane >= off) s += u;
        }
        if (idx < NB) bbase[idx] = carry + s - v;
        carry += __shfl(s, 63);
    }
}

// one block per bucket: hist(512) -> scan -> rowptr/dinv -> place col
__global__ __launch_bounds__(256) void build_kernel(
        const unsigned int* __restrict__ binbuf, const int* __restrict__ gfill,
        const int* __restrict__ bbase, int* __restrict__ rowptr,
        float* __restrict__ dinv, int* __restrict__ col,
        int NB, int C, int N, int E) {
    __shared__ int h[512];
    __shared__ int hs[512];
    int b = blockIdx.x, tid = threadIdx.x;
    int cnt = gfill[b];
    const unsigned int* p = binbuf + (size_t)b * C;
    for (int i = tid; i < 512; i += 256) h[i] = 0;
    __syncthreads();
    for (int i = tid; i < cnt; i += 256) atomicAdd(&h[p[i] >> 17], 1);
    __syncthreads();
    if (tid < 64) {                       // wave 0: exclusive scan h->hs
        int carry = 0;
        for (int base = 0; base < 512; base += 64) {
            int v = h[base + tid];
            int s = v;
            #pragma unroll
            for (int off = 1; off < 64; off <<= 1) {
                int u = __shfl_up(s, off);
                if (tid >= off) s += u;
            }
            hs[base + tid] = carry + s - v;
            carry += __shfl(s, 63);
        }
    }
    __syncthreads();
    int base = bbase[b];
    for (int i = tid; i < 512; i += 256) {
        int node = b * 512 + i;
        if (node < N) {
            rowptr[node] = base + hs[i];
            dinv[node] = 1.0f / sqrtf((float)(h[i] + 1));   // +1 self loop
        }
    }
    if (b == 0 && tid == 0) rowptr[N] = E;
    __syncthreads();
    for (int i = tid; i < cnt; i += 256) {  // place (hs doubles as cursor)
        unsigned int u = p[i];
        int local = u >> 17;
        int pos = atomicAdd(&hs[local], 1);
        col[base + pos] = (int)(u & 0x1FFFFu);
    }
}

// ---- weight pre-pack into MFMA B-fragment order ---------------------------

__global__ void pack_kernel(const float* __restrict__ W0, const float* __restrict__ W1,
                            const float* __restrict__ W2, const float* __restrict__ W3,
                            unsigned short* __restrict__ P0, unsigned short* __restrict__ P1,
                            unsigned short* __restrict__ P2, unsigned short* __restrict__ P3) {
    int which = blockIdx.x >> 3;
    const float* W = which == 0 ? W0 : which == 1 ? W1 : which == 2 ? W2 : W3;
    unsigned short* P = which == 0 ? P0 : which == 1 ? P1 : which == 2 ? P2 : P3;
    int f = (blockIdx.x & 7) * 256 + threadIdx.x;   // fragment id 0..2047
    int lane = f & 63, nt = (f >> 6) & 7, kc = f >> 9;
    int kbase = kc * 32 + (lane >> 4) * 8;
    int ncol = nt * 16 + (lane & 15);
    short8 frag;
    #pragma unroll
    for (int j = 0; j < 8; ++j)
        frag[j] = (short)f2bf(W[(size_t)(kbase + j) * 128 + ncol]);
    *((short8*)(P + (size_t)f * 8)) = frag;
}

// ---- input layer: t' = dinv_i * (x @ W_s)  (N x 3 @ 3 x 128) --------------

__global__ void in_gemm_kernel(const float* __restrict__ x, const float* __restrict__ W,
                               const float* __restrict__ dinv,
                               unsigned short* __restrict__ t, int n) {
    int g = blockIdx.x * 256 + threadIdx.x;
    int i = g >> 6, c2 = g & 63;
    if (i >= n) return;
    float x0 = x[i * 3], x1 = x[i * 3 + 1], x2 = x[i * 3 + 2];
    float d = dinv[i];
    int c = c2 * 2;
    float v0 = d * (x0 * W[c]     + x1 * W[128 + c]     + x2 * W[256 + c]);
    float v1 = d * (x0 * W[c + 1] + x1 * W[128 + c + 1] + x2 * W[256 + c + 1]);
    unsigned int o = (unsigned int)f2bf(v0) | ((unsigned int)f2bf(v1) << 16);
    ((unsigned int*)t)[(size_t)i * 64 + c2] = o;
}

// ---- aggregation: out_i = relu( d_i * (t'_i + sum_j t'_j) + b ) -----------
// One wave per node. Lane = (edge-group g in 0..3) x (col-position lq in
// 0..15). One uint4 load per lane fetches 16 B => 4 whole edge rows per
// VMEM instruction. Fold groups with shfl_xor(16,32); 16 lanes finalize.

__global__ __launch_bounds__(256) void agg_kernel(
        const unsigned short* __restrict__ t, const int* __restrict__ rowptr,
        const int* __restrict__ col, const float* __restrict__ dinv,
        const float* __restrict__ bias, unsigned short* __restrict__ out, int n) {
    int node = blockIdx.x * 4 + (threadIdx.x >> 6);
    int lane = threadIdx.x & 63;
    if (node >= n) return;
    int g = lane >> 4, lq = lane & 15;
    float acc[8];
    #pragma unroll
    for (int i = 0; i < 8; ++i) acc[i] = 0.f;

    int beg = rowptr[node], end = rowptr[node + 1];
    int deg = end - beg;
    for (int base = 0; base < deg; base += 64) {
        int m = deg - base; if (m > 64) m = 64;
        int jv = (lane < m) ? col[beg + base + lane] : node;
        for (int e = 0; e < m; e += 16) {
            uint4 v[4];
            #pragma unroll
            for (int q = 0; q < 4; ++q) {
                int eq = e + q * 4 + g;                 // <= 63 always
                int j = __shfl(jv, eq);
                v[q] = ((const uint4*)(t + (size_t)j * 128))[lq];
            }
            #pragma unroll
            for (int q = 0; q < 4; ++q) {
                uint4 u = v[q];
                if (e + q * 4 + g >= m) { u.x = 0u; u.y = 0u; u.z = 0u; u.w = 0u; }
                acc[0] += bflo(u.x); acc[1] += bfhi(u.x);
                acc[2] += bflo(u.y); acc[3] += bfhi(u.y);
                acc[4] += bflo(u.z); acc[5] += bfhi(u.z);
                acc[6] += bflo(u.w); acc[7] += bfhi(u.w);
            }
        }
    }
    // fold 4 edge-groups
    #pragma unroll
    for (int i = 0; i < 8; ++i) acc[i] += __shfl_xor(acc[i], 16);
    #pragma unroll
    for (int i = 0; i < 8; ++i) acc[i] += __shfl_xor(acc[i], 32);

    if (g == 0) {                                       // 16 lanes finalize row
        uint4 s = ((const uint4*)(t + (size_t)node * 128))[lq];   // self term
        acc[0] += bflo(s.x); acc[1] += bfhi(s.x);
        acc[2] += bflo(s.y); acc[3] += bfhi(s.y);
        acc[4] += bflo(s.z); acc[5] += bfhi(s.z);
        acc[6] += bflo(s.w); acc[7] += bfhi(s.w);
        float di = dinv[node];
        const float4* b4 = (const float4*)bias;
        float4 b0 = b4[lq * 2], b1 = b4[lq * 2 + 1];
        float o0 = fmaxf(di * acc[0] + b0.x, 0.f), o1 = fmaxf(di * acc[1] + b0.y, 0.f);
        float o2 = fmaxf(di * acc[2] + b0.z, 0.f), o3 = fmaxf(di * acc[3] + b0.w, 0.f);
        float o4 = fmaxf(di * acc[4] + b1.x, 0.f), o5 = fmaxf(di * acc[5] + b1.y, 0.f);
        float o6 = fmaxf(di * acc[6] + b1.z, 0.f), o7 = fmaxf(di * acc[7] + b1.w, 0.f);
        uint4 o;
        o.x = (unsigned int)f2bf(o0) | ((unsigned int)f2bf(o1) << 16);
        o.y = (unsigned int)f2bf(o2) | ((unsigned int)f2bf(o3) << 16);
        o.z = (unsigned int)f2bf(o4) | ((unsigned int)f2bf(o5) << 16);
        o.w = (unsigned int)f2bf(o6) | ((unsigned int)f2bf(o7) << 16);
        ((uint4*)(out + (size_t)node * 128))[lq] = o;
    }
}

// ---- dense 128x128 GEMM via MFMA 16x16x32 bf16 ----------------------------

template <bool SCALE_DINV, bool BIAS_RELU>
__global__ __launch_bounds__(256) void gemm_mfma_kernel(
        const unsigned short* __restrict__ A, const unsigned short* __restrict__ Wp,
        const float* __restrict__ bias, const float* __restrict__ dinv,
        unsigned short* __restrict__ out, int n) {
    __shared__ unsigned short Ws[16384];   // 32 KB packed weights
    int tid = threadIdx.x;
    {
        const int4* s = (const int4*)Wp;
        int4* d = (int4*)Ws;
        #pragma unroll
        for (int i = 0; i < 8; ++i) d[tid + 256 * i] = s[tid + 256 * i];
    }
    int wave = tid >> 6, lane = tid & 63;
    int quad = lane >> 4, mrow = lane & 15;
    int row0 = blockIdx.x * 64 + wave * 16;
    __syncthreads();

    int arow = row0 + mrow; if (arow >= n) arow = n - 1;
    const unsigned short* abase = A + (size_t)arow * 128 + quad * 8;
    short8 af[4];
    #pragma unroll
    for (int kc = 0; kc < 4; ++kc)
        af[kc] = *((const short8*)(abase + kc * 32));

    floatx4 acc[8];
    #pragma unroll
    for (int t = 0; t < 8; ++t) acc[t] = (floatx4){0.f, 0.f, 0.f, 0.f};

    #pragma unroll
    for (int kc = 0; kc < 4; ++kc) {
        #pragma unroll
        for (int nt = 0; nt < 8; ++nt) {
            short8 bf = *((const short8*)(Ws + ((kc * 8 + nt) * 64 + lane) * 8));
            acc[nt] = __builtin_amdgcn_mfma_f32_16x16x32_bf16(af[kc], bf, acc[nt], 0, 0, 0);
        }
    }

    float dv[4];
    if (SCALE_DINV) {
        #pragma unroll
        for (int r = 0; r < 4; ++r) {
            int row = row0 + quad * 4 + r;
            dv[r] = (row < n) ? dinv[row] : 0.f;
        }
    }
    #pragma unroll
    for (int nt = 0; nt < 8; ++nt) {
        int colc = nt * 16 + mrow;
        float bcol = BIAS_RELU ? bias[colc] : 0.f;
        #pragma unroll
        for (int r = 0; r < 4; ++r) {
            int row = row0 + quad * 4 + r;
            if (row < n) {
                float v = acc[nt][r];
                if (BIAS_RELU) v = fmaxf(v + bcol, 0.f);
                if (SCALE_DINV) v *= dv[r];
                out[(size_t)row * 128 + colc] = f2bf(v);
            }
        }
    }
}

// ---- output layer: out = h @ W_ed + b_ed + x  (128 -> 3) ------------------

__global__ __launch_bounds__(256) void out_kernel(
        const unsigned short* __restrict__ h, const float* __restrict__ W,
        const float* __restrict__ bias, const float* __restrict__ x,
        float* __restrict__ out, int n) {
    int node = blockIdx.x * 4 + (threadIdx.x >> 6);
    int lane = threadIdx.x & 63;
    if (node >= n) return;
    unsigned int hv = ((const unsigned int*)(h + (size_t)node * 128))[lane];
    float h0 = bflo(hv), h1 = bfhi(hv);
    int c = lane * 2;
    float s0 = h0 * W[c * 3]     + h1 * W[(c + 1) * 3];
    float s1 = h0 * W[c * 3 + 1] + h1 * W[(c + 1) * 3 + 1];
    float s2 = h0 * W[c * 3 + 2] + h1 * W[(c + 1) * 3 + 2];
    #pragma unroll
    for (int off = 32; off > 0; off >>= 1) {
        s0 += __shfl_down(s0, off);
        s1 += __shfl_down(s1, off);
        s2 += __shfl_down(s2, off);
    }
    if (lane == 0) {
        out[node * 3 + 0] = s0 + bias[0] + x[node * 3 + 0];
        out[node * 3 + 1] = s1 + bias[1] + x[node * 3 + 1];
        out[node * 3 + 2] = s2 + bias[2] + x[node * 3 + 2];
    }
}

// ---------------------------------------------------------------------------

extern "C" void kernel_launch(void* const* d_in, const int* in_sizes, int n_in,
                              void* d_out, int out_size, void* d_ws, size_t ws_size,
                              hipStream_t stream) {
    const float* x    = (const float*)d_in[0];
    const int*   ei   = (const int*)d_in[1];
    const float* W_s  = (const float*)d_in[2];
    const float* b_s  = (const float*)d_in[3];
    const float* W_m  = (const float*)d_in[4];
    const float* b_m  = (const float*)d_in[5];
    const float* W_e  = (const float*)d_in[6];
    const float* b_e  = (const float*)d_in[7];
    const float* W_sd = (const float*)d_in[8];
    const float* b_sd = (const float*)d_in[9];
    const float* W_md = (const float*)d_in[10];
    const float* b_md = (const float*)d_in[11];
    const float* W_ed = (const float*)d_in[12];
    const float* b_ed = (const float*)d_in[13];
    float* outp = (float*)d_out;

    const int N = in_sizes[0] / 3;
    const int E = in_sizes[1] / 2;
    const int* src = ei;
    const int* dst = ei + E;

    const int NB = (N + 511) >> 9;                 // 512-node buckets
    const int C  = (((E / NB) * 3 / 2) + 255) & ~255;   // segment cap, 1.5x mean

    char* p = (char*)d_ws;
    auto carve = [&](size_t bytes) {
        void* r = (void*)p;
        p += (bytes + 255) & ~(size_t)255;
        return r;
    };
    int*   rowptr = (int*)  carve((size_t)(N + 1) * 4);
    int*   col    = (int*)  carve((size_t)E * 4);
    float* dinv   = (float*)carve((size_t)N * 4);
    int*   gfill  = (int*)  carve((size_t)NB * 4);
    int*   bbase  = (int*)  carve((size_t)NB * 4);
    unsigned int* binbuf = (unsigned int*)carve((size_t)NB * C * 4);
    unsigned short* Wp_m  = (unsigned short*)carve(16384 * 2);
    unsigned short* Wp_e  = (unsigned short*)carve(16384 * 2);
    unsigned short* Wp_sd = (unsigned short*)carve(16384 * 2);
    unsigned short* Wp_md = (unsigned short*)carve(16384 * 2);
    unsigned short* A  = (unsigned short*)carve((size_t)N * 128 * 2);
    unsigned short* Bm = (unsigned short*)carve((size_t)N * 128 * 2);
    (void)ws_size;

    const int gBin = (E + BIN_CH - 1) / BIN_CH;
    const int gNode4 = (N + 3) / 4;
    const int gRow64 = (N + 63) / 64;

    // graph build
    hipMemsetAsync(gfill, 0, (size_t)NB * 4, stream);
    bin_kernel<<<gBin, 512, 0, stream>>>(src, dst, gfill, binbuf, NB, C, E);
    bscan_kernel<<<1, 64, 0, stream>>>(gfill, bbase, NB);
    build_kernel<<<NB, 256, 0, stream>>>(binbuf, gfill, bbase, rowptr, dinv, col, NB, C, N, E);

    // weight packs
    pack_kernel<<<32, 256, 0, stream>>>(W_m, W_e, W_sd, W_md, Wp_m, Wp_e, Wp_sd, Wp_md);

    // encoder
    in_gemm_kernel<<<(N * 64 + 255) / 256, 256, 0, stream>>>(x, W_s, dinv, Bm, N);
    agg_kernel<<<gNode4, 256, 0, stream>>>(Bm, rowptr, col, dinv, b_s, A, N);

    gemm_mfma_kernel<true, false><<<gRow64, 256, 0, stream>>>(A, Wp_m, nullptr, dinv, Bm, N);
    agg_kernel<<<gNode4, 256, 0, stream>>>(Bm, rowptr, col, dinv, b_m, A, N);

    gemm_mfma_kernel<true, false><<<gRow64, 256, 0, stream>>>(A, Wp_m, nullptr, dinv, Bm, N);
    agg_kernel<<<gNode4, 256, 0, stream>>>(Bm, rowptr, col, dinv, b_m, A, N);

    gemm_mfma_kernel<true, false><<<gRow64, 256, 0, stream>>>(A, Wp_e, nullptr, dinv, Bm, N);
    agg_kernel<<<gNode4, 256, 0, stream>>>(Bm, rowptr, col, dinv, b_e, A, N);

    // decoder
    gemm_mfma_kernel<false, true><<<gRow64, 256, 0, stream>>>(A, Wp_sd, b_sd, nullptr, Bm, N);
    gemm_mfma_kernel<false, true><<<gRow64, 256, 0, stream>>>(Bm, Wp_md, b_md, nullptr, A, N);
    gemm_mfma_kernel<false, true><<<gRow64, 256, 0, stream>>>(A, Wp_md, b_md, nullptr, Bm, N);
    out_kernel<<<gNode4, 256, 0, stream>>>(Bm, W_ed, b_ed, x, outp, N);
}

// Round 7
// 454.063 us; speedup vs baseline: 1.1503x; 1.1503x over previous
//
#include <hip/hip_runtime.h>

// ---------------------------------------------------------------------------
// GCN encoder (4 conv layers, shared CSR graph) + 3-layer MLP decoder.
// Round 7: gather operand (t' message rows) stored as fp8 e4m3 — halves the
// per-XCD L2 re-fetch floor (FETCH ~= 8 XCD x matrix size) that bounds agg.
// Accumulation fp32, GEMM A/W stay bf16; only gathered rows are fp8.
// ---------------------------------------------------------------------------

typedef __attribute__((ext_vector_type(8))) short short8;
typedef __attribute__((ext_vector_type(4))) float floatx4;
typedef __attribute__((ext_vector_type(2))) float floatx2;

#define BIN_CH 8192          // edges per bin block
#define NBMAX 512            // max buckets supported

__device__ __forceinline__ unsigned short f2bf(float f) {
    unsigned int u = __float_as_uint(f);
    u += 0x7fffu + ((u >> 16) & 1u);          // round-to-nearest-even
    return (unsigned short)(u >> 16);
}
__device__ __forceinline__ float bflo(unsigned int u) { return __uint_as_float(u << 16); }
__device__ __forceinline__ float bfhi(unsigned int u) { return __uint_as_float(u & 0xffff0000u); }
__device__ __forceinline__ unsigned char f2fp8(float f) {
    return (unsigned char)(__builtin_amdgcn_cvt_pk_fp8_f32(f, f, 0, false) & 0xFF);
}

// ---- graph build ----------------------------------------------------------

// block-aggregated binning: LDS hist -> local scan -> 1 global atomic per
// (block,bucket) run reservation -> dense run writes into bucket segments.
__global__ __launch_bounds__(512) void bin_kernel(
        const int* __restrict__ src, const int* __restrict__ dst,
        int* __restrict__ gfill, unsigned int* __restrict__ binbuf,
        int NB, int C, int E) {
    __shared__ int hist[NBMAX];
    __shared__ int start[NBMAX];
    __shared__ int dstoff[NBMAX];
    int tid = threadIdx.x;
    int e0 = blockIdx.x * BIN_CH;
    for (int i = tid; i < NB; i += 512) hist[i] = 0;
    __syncthreads();
    for (int i = tid; i < BIN_CH; i += 512) {
        int e = e0 + i;
        if (e < E) atomicAdd(&hist[dst[e] >> 9], 1);
    }
    __syncthreads();
    if (tid < 64) {                       // wave 0: exclusive scan hist->start
        int carry = 0;
        for (int base = 0; base < NB; base += 64) {
            int idx = base + tid;
            int v = (idx < NB) ? hist[idx] : 0;
            int s = v;
            #pragma unroll
            for (int off = 1; off < 64; off <<= 1) {
                int u = __shfl_up(s, off);
                if (tid >= off) s += u;
            }
            if (idx < NB) start[idx] = carry + s - v;
            carry += __shfl(s, 63);
        }
    }
    __syncthreads();
    for (int i = tid; i < NB; i += 512) { // reserve global runs
        int cnt = hist[i];
        int g = cnt ? atomicAdd(&gfill[i], cnt) : 0;
        dstoff[i] = g - start[i];
        hist[i] = start[i];               // reuse as local cursor
    }
    __syncthreads();
    for (int i = tid; i < BIN_CH; i += 512) {
        int e = e0 + i;
        if (e >= E) continue;
        int d = dst[e];
        int b = d >> 9;
        int slot = atomicAdd(&hist[b], 1);            // local rank
        int gidx = b * C + dstoff[b] + slot;
        if (gidx < (b + 1) * C)
            binbuf[gidx] = (unsigned int)src[e] | ((unsigned int)(d & 511) << 17);
    }
}

// exclusive scan over NB bucket sizes (1 wave)
__global__ void bscan_kernel(const int* __restrict__ gfill, int* __restrict__ bbase, int NB) {
    int lane = threadIdx.x;
    int carry = 0;
    for (int base = 0; base < NB; base += 64) {
        int idx = base + lane;
        int v = (idx < NB) ? gfill[idx] : 0;
        int s = v;
        #pragma unroll
        for (int off = 1; off < 64; off <<= 1) {
            int u = __shfl_up(s, off);
            if (lane >= off) s += u;
        }
        if (idx < NB) bbase[idx] = carry + s - v;
        carry += __shfl(s, 63);
    }
}

// one block per bucket: hist(512) -> scan -> rowptr/dinv -> place col
__global__ __launch_bounds__(256) void build_kernel(
        const unsigned int* __restrict__ binbuf, const int* __restrict__ gfill,
        const int* __restrict__ bbase, int* __restrict__ rowptr,
        float* __restrict__ dinv, int* __restrict__ col,
        int NB, int C, int N, int E) {
    __shared__ int h[512];
    __shared__ int hs[512];
    int b = blockIdx.x, tid = threadIdx.x;
    int cnt = gfill[b];
    const unsigned int* p = binbuf + (size_t)b * C;
    for (int i = tid; i < 512; i += 256) h[i] = 0;
    __syncthreads();
    for (int i = tid; i < cnt; i += 256) atomicAdd(&h[p[i] >> 17], 1);
    __syncthreads();
    if (tid < 64) {                       // wave 0: exclusive scan h->hs
        int carry = 0;
        for (int base = 0; base < 512; base += 64) {
            int v = h[base + tid];
            int s = v;
            #pragma unroll
            for (int off = 1; off < 64; off <<= 1) {
                int u = __shfl_up(s, off);
                if (tid >= off) s += u;
            }
            hs[base + tid] = carry + s - v;
            carry += __shfl(s, 63);
        }
    }
    __syncthreads();
    int base = bbase[b];
    for (int i = tid; i < 512; i += 256) {
        int node = b * 512 + i;
        if (node < N) {
            rowptr[node] = base + hs[i];
            dinv[node] = 1.0f / sqrtf((float)(h[i] + 1));   // +1 self loop
        }
    }
    if (b == 0 && tid == 0) rowptr[N] = E;
    __syncthreads();
    for (int i = tid; i < cnt; i += 256) {  // place (hs doubles as cursor)
        unsigned int u = p[i];
        int local = u >> 17;
        int pos = atomicAdd(&hs[local], 1);
        col[base + pos] = (int)(u & 0x1FFFFu);
    }
}

// ---- weight pre-pack into MFMA B-fragment order ---------------------------

__global__ void pack_kernel(const float* __restrict__ W0, const float* __restrict__ W1,
                            const float* __restrict__ W2, const float* __restrict__ W3,
                            unsigned short* __restrict__ P0, unsigned short* __restrict__ P1,
                            unsigned short* __restrict__ P2, unsigned short* __restrict__ P3) {
    int which = blockIdx.x >> 3;
    const float* W = which == 0 ? W0 : which == 1 ? W1 : which == 2 ? W2 : W3;
    unsigned short* P = which == 0 ? P0 : which == 1 ? P1 : which == 2 ? P2 : P3;
    int f = (blockIdx.x & 7) * 256 + threadIdx.x;   // fragment id 0..2047
    int lane = f & 63, nt = (f >> 6) & 7, kc = f >> 9;
    int kbase = kc * 32 + (lane >> 4) * 8;
    int ncol = nt * 16 + (lane & 15);
    short8 frag;
    #pragma unroll
    for (int j = 0; j < 8; ++j)
        frag[j] = (short)f2bf(W[(size_t)(kbase + j) * 128 + ncol]);
    *((short8*)(P + (size_t)f * 8)) = frag;
}

// ---- input layer: t' = fp8( dinv_i * (x @ W_s) )  (N x 3 @ 3 x 128) -------

__global__ void in_gemm_kernel(const float* __restrict__ x, const float* __restrict__ W,
                               const float* __restrict__ dinv,
                               unsigned char* __restrict__ t8, int n) {
    int g = blockIdx.x * 256 + threadIdx.x;
    int i = g >> 6, c2 = g & 63;
    if (i >= n) return;
    float x0 = x[i * 3], x1 = x[i * 3 + 1], x2 = x[i * 3 + 2];
    float d = dinv[i];
    int c = c2 * 2;
    float v0 = d * (x0 * W[c]     + x1 * W[128 + c]     + x2 * W[256 + c]);
    float v1 = d * (x0 * W[c + 1] + x1 * W[128 + c + 1] + x2 * W[256 + c + 1]);
    unsigned int pk = __builtin_amdgcn_cvt_pk_fp8_f32(v0, v1, 0, false);
    ((unsigned short*)t8)[(size_t)i * 64 + c2] = (unsigned short)(pk & 0xFFFF);
}

// ---- aggregation: out_i = relu( d_i * (t'_i + sum_j t'_j) + b ) -----------
// t' rows are fp8 e4m3 (128 B), already carry d_j. One wave per node.
// Lane = (edge-group g 0..3) x (col-pos lq 0..15): one uint2 (8 B) load per
// lane => 4 whole edge rows per VMEM inst. shfl_xor fold; bf16 output.

__global__ __launch_bounds__(256) void agg_kernel(
        const unsigned char* __restrict__ t8, const int* __restrict__ rowptr,
        const int* __restrict__ col, const float* __restrict__ dinv,
        const float* __restrict__ bias, unsigned short* __restrict__ out, int n) {
    int node = blockIdx.x * 4 + (threadIdx.x >> 6);
    int lane = threadIdx.x & 63;
    if (node >= n) return;
    int g = lane >> 4, lq = lane & 15;
    float acc[8];
    #pragma unroll
    for (int i = 0; i < 8; ++i) acc[i] = 0.f;

    int beg = rowptr[node], end = rowptr[node + 1];
    int deg = end - beg;
    for (int base = 0; base < deg; base += 64) {
        int m = deg - base; if (m > 64) m = 64;
        int jv = (lane < m) ? col[beg + base + lane] : node;
        for (int e = 0; e < m; e += 16) {
            uint2 v[4];
            #pragma unroll
            for (int q = 0; q < 4; ++q) {
                int eq = e + q * 4 + g;                 // <= 63 always
                int j = __shfl(jv, eq);
                v[q] = ((const uint2*)(t8 + (size_t)j * 128))[lq];
            }
            #pragma unroll
            for (int q = 0; q < 4; ++q) {
                uint2 u = v[q];
                if (e + q * 4 + g >= m) { u.x = 0u; u.y = 0u; }   // fp8 0 == 0.0
                floatx2 f0 = __builtin_amdgcn_cvt_pk_f32_fp8(u.x, false);
                floatx2 f1 = __builtin_amdgcn_cvt_pk_f32_fp8(u.x, true);
                floatx2 f2 = __builtin_amdgcn_cvt_pk_f32_fp8(u.y, false);
                floatx2 f3 = __builtin_amdgcn_cvt_pk_f32_fp8(u.y, true);
                acc[0] += f0.x; acc[1] += f0.y; acc[2] += f1.x; acc[3] += f1.y;
                acc[4] += f2.x; acc[5] += f2.y; acc[6] += f3.x; acc[7] += f3.y;
            }
        }
    }
    // fold 4 edge-groups
    #pragma unroll
    for (int i = 0; i < 8; ++i) acc[i] += __shfl_xor(acc[i], 16);
    #pragma unroll
    for (int i = 0; i < 8; ++i) acc[i] += __shfl_xor(acc[i], 32);

    if (g == 0) {                                       // 16 lanes finalize row
        uint2 s = ((const uint2*)(t8 + (size_t)node * 128))[lq];   // self term
        floatx2 s0 = __builtin_amdgcn_cvt_pk_f32_fp8(s.x, false);
        floatx2 s1 = __builtin_amdgcn_cvt_pk_f32_fp8(s.x, true);
        floatx2 s2 = __builtin_amdgcn_cvt_pk_f32_fp8(s.y, false);
        floatx2 s3 = __builtin_amdgcn_cvt_pk_f32_fp8(s.y, true);
        acc[0] += s0.x; acc[1] += s0.y; acc[2] += s1.x; acc[3] += s1.y;
        acc[4] += s2.x; acc[5] += s2.y; acc[6] += s3.x; acc[7] += s3.y;
        float di = dinv[node];
        const float4* b4 = (const float4*)bias;
        float4 b0 = b4[lq * 2], b1 = b4[lq * 2 + 1];
        float o0 = fmaxf(di * acc[0] + b0.x, 0.f), o1 = fmaxf(di * acc[1] + b0.y, 0.f);
        float o2 = fmaxf(di * acc[2] + b0.z, 0.f), o3 = fmaxf(di * acc[3] + b0.w, 0.f);
        float o4 = fmaxf(di * acc[4] + b1.x, 0.f), o5 = fmaxf(di * acc[5] + b1.y, 0.f);
        float o6 = fmaxf(di * acc[6] + b1.z, 0.f), o7 = fmaxf(di * acc[7] + b1.w, 0.f);
        uint4 o;
        o.x = (unsigned int)f2bf(o0) | ((unsigned int)f2bf(o1) << 16);
        o.y = (unsigned int)f2bf(o2) | ((unsigned int)f2bf(o3) << 16);
        o.z = (unsigned int)f2bf(o4) | ((unsigned int)f2bf(o5) << 16);
        o.w = (unsigned int)f2bf(o6) | ((unsigned int)f2bf(o7) << 16);
        ((uint4*)(out + (size_t)node * 128))[lq] = o;
    }
}

// ---- dense 128x128 GEMM via MFMA 16x16x32 bf16 ----------------------------
// ENC: out = fp8( dinv[row] * (A@W) )   (encoder, feeds next agg gather)
// !ENC: out = bf16( relu(A@W + bias) )  (decoder)

template <bool ENC>
__global__ __launch_bounds__(256) void gemm_mfma_kernel(
        const unsigned short* __restrict__ A, const unsigned short* __restrict__ Wp,
        const float* __restrict__ bias, const float* __restrict__ dinv,
        void* __restrict__ outp, int n) {
    __shared__ unsigned short Ws[16384];   // 32 KB packed weights
    int tid = threadIdx.x;
    {
        const int4* s = (const int4*)Wp;
        int4* d = (int4*)Ws;
        #pragma unroll
        for (int i = 0; i < 8; ++i) d[tid + 256 * i] = s[tid + 256 * i];
    }
    int wave = tid >> 6, lane = tid & 63;
    int quad = lane >> 4, mrow = lane & 15;
    int row0 = blockIdx.x * 64 + wave * 16;
    __syncthreads();

    int arow = row0 + mrow; if (arow >= n) arow = n - 1;
    const unsigned short* abase = A + (size_t)arow * 128 + quad * 8;
    short8 af[4];
    #pragma unroll
    for (int kc = 0; kc < 4; ++kc)
        af[kc] = *((const short8*)(abase + kc * 32));

    floatx4 acc[8];
    #pragma unroll
    for (int t = 0; t < 8; ++t) acc[t] = (floatx4){0.f, 0.f, 0.f, 0.f};

    #pragma unroll
    for (int kc = 0; kc < 4; ++kc) {
        #pragma unroll
        for (int nt = 0; nt < 8; ++nt) {
            short8 bf = *((const short8*)(Ws + ((kc * 8 + nt) * 64 + lane) * 8));
            acc[nt] = __builtin_amdgcn_mfma_f32_16x16x32_bf16(af[kc], bf, acc[nt], 0, 0, 0);
        }
    }

    float dv[4];
    if (ENC) {
        #pragma unroll
        for (int r = 0; r < 4; ++r) {
            int row = row0 + quad * 4 + r;
            dv[r] = (row < n) ? dinv[row] : 0.f;
        }
    }
    #pragma unroll
    for (int nt = 0; nt < 8; ++nt) {
        int colc = nt * 16 + mrow;
        float bcol = ENC ? 0.f : bias[colc];
        #pragma unroll
        for (int r = 0; r < 4; ++r) {
            int row = row0 + quad * 4 + r;
            if (row < n) {
                float v = acc[nt][r];
                if (ENC) {
                    v *= dv[r];
                    ((unsigned char*)outp)[(size_t)row * 128 + colc] = f2fp8(v);
                } else {
                    v = fmaxf(v + bcol, 0.f);
                    ((unsigned short*)outp)[(size_t)row * 128 + colc] = f2bf(v);
                }
            }
        }
    }
}

// ---- output layer: out = h @ W_ed + b_ed + x  (128 -> 3) ------------------

__global__ __launch_bounds__(256) void out_kernel(
        const unsigned short* __restrict__ h, const float* __restrict__ W,
        const float* __restrict__ bias, const float* __restrict__ x,
        float* __restrict__ out, int n) {
    int node = blockIdx.x * 4 + (threadIdx.x >> 6);
    int lane = threadIdx.x & 63;
    if (node >= n) return;
    unsigned int hv = ((const unsigned int*)(h + (size_t)node * 128))[lane];
    float h0 = bflo(hv), h1 = bfhi(hv);
    int c = lane * 2;
    float s0 = h0 * W[c * 3]     + h1 * W[(c + 1) * 3];
    float s1 = h0 * W[c * 3 + 1] + h1 * W[(c + 1) * 3 + 1];
    float s2 = h0 * W[c * 3 + 2] + h1 * W[(c + 1) * 3 + 2];
    #pragma unroll
    for (int off = 32; off > 0; off >>= 1) {
        s0 += __shfl_down(s0, off);
        s1 += __shfl_down(s1, off);
        s2 += __shfl_down(s2, off);
    }
    if (lane == 0) {
        out[node * 3 + 0] = s0 + bias[0] + x[node * 3 + 0];
        out[node * 3 + 1] = s1 + bias[1] + x[node * 3 + 1];
        out[node * 3 + 2] = s2 + bias[2] + x[node * 3 + 2];
    }
}

// ---------------------------------------------------------------------------

extern "C" void kernel_launch(void* const* d_in, const int* in_sizes, int n_in,
                              void* d_out, int out_size, void* d_ws, size_t ws_size,
                              hipStream_t stream) {
    const float* x    = (const float*)d_in[0];
    const int*   ei   = (const int*)d_in[1];
    const float* W_s  = (const float*)d_in[2];
    const float* b_s  = (const float*)d_in[3];
    const float* W_m  = (const float*)d_in[4];
    const float* b_m  = (const float*)d_in[5];
    const float* W_e  = (const float*)d_in[6];
    const float* b_e  = (const float*)d_in[7];
    const float* W_sd = (const float*)d_in[8];
    const float* b_sd = (const float*)d_in[9];
    const float* W_md = (const float*)d_in[10];
    const float* b_md = (const float*)d_in[11];
    const float* W_ed = (const float*)d_in[12];
    const float* b_ed = (const float*)d_in[13];
    float* outp = (float*)d_out;

    const int N = in_sizes[0] / 3;
    const int E = in_sizes[1] / 2;
    const int* src = ei;
    const int* dst = ei + E;

    const int NB = (N + 511) >> 9;                 // 512-node buckets
    const int C  = (((E / NB) * 3 / 2) + 255) & ~255;   // segment cap, 1.5x mean

    char* p = (char*)d_ws;
    auto carve = [&](size_t bytes) {
        void* r = (void*)p;
        p += (bytes + 255) & ~(size_t)255;
        return r;
    };
    int*   rowptr = (int*)  carve((size_t)(N + 1) * 4);
    int*   col    = (int*)  carve((size_t)E * 4);
    float* dinv   = (float*)carve((size_t)N * 4);
    int*   gfill  = (int*)  carve((size_t)NB * 4);
    int*   bbase  = (int*)  carve((size_t)NB * 4);
    unsigned int* binbuf = (unsigned int*)carve((size_t)NB * C * 4);
    unsigned short* Wp_m  = (unsigned short*)carve(16384 * 2);
    unsigned short* Wp_e  = (unsigned short*)carve(16384 * 2);
    unsigned short* Wp_sd = (unsigned short*)carve(16384 * 2);
    unsigned short* Wp_md = (unsigned short*)carve(16384 * 2);
    unsigned char*  T8 = (unsigned char*) carve((size_t)N * 128);
    unsigned short* A  = (unsigned short*)carve((size_t)N * 128 * 2);
    unsigned short* Bm = (unsigned short*)carve((size_t)N * 128 * 2);
    (void)ws_size;

    const int gBin = (E + BIN_CH - 1) / BIN_CH;
    const int gNode4 = (N + 3) / 4;
    const int gRow64 = (N + 63) / 64;

    // graph build
    hipMemsetAsync(gfill, 0, (size_t)NB * 4, stream);
    bin_kernel<<<gBin, 512, 0, stream>>>(src, dst, gfill, binbuf, NB, C, E);
    bscan_kernel<<<1, 64, 0, stream>>>(gfill, bbase, NB);
    build_kernel<<<NB, 256, 0, stream>>>(binbuf, gfill, bbase, rowptr, dinv, col, NB, C, N, E);

    // weight packs
    pack_kernel<<<32, 256, 0, stream>>>(W_m, W_e, W_sd, W_md, Wp_m, Wp_e, Wp_sd, Wp_md);

    // encoder (t' in fp8, h in bf16)
    in_gemm_kernel<<<(N * 64 + 255) / 256, 256, 0, stream>>>(x, W_s, dinv, T8, N);
    agg_kernel<<<gNode4, 256, 0, stream>>>(T8, rowptr, col, dinv, b_s, A, N);

    gemm_mfma_kernel<true><<<gRow64, 256, 0, stream>>>(A, Wp_m, nullptr, dinv, T8, N);
    agg_kernel<<<gNode4, 256, 0, stream>>>(T8, rowptr, col, dinv, b_m, A, N);

    gemm_mfma_kernel<true><<<gRow64, 256, 0, stream>>>(A, Wp_m, nullptr, dinv, T8, N);
    agg_kernel<<<gNode4, 256, 0, stream>>>(T8, rowptr, col, dinv, b_m, A, N);

    gemm_mfma_kernel<true><<<gRow64, 256, 0, stream>>>(A, Wp_e, nullptr, dinv, T8, N);
    agg_kernel<<<gNode4, 256, 0, stream>>>(T8, rowptr, col, dinv, b_e, A, N);

    // decoder (bf16 throughout)
    gemm_mfma_kernel<false><<<gRow64, 256, 0, stream>>>(A, Wp_sd, b_sd, nullptr, Bm, N);
    gemm_mfma_kernel<false><<<gRow64, 256, 0, stream>>>(Bm, Wp_md, b_md, nullptr, A, N);
    gemm_mfma_kernel<false><<<gRow64, 256, 0, stream>>>(A, Wp_md, b_md, nullptr, Bm, N);
    out_kernel<<<gNode4, 256, 0, stream>>>(Bm, W_ed, b_ed, x, outp, N);
}

// Round 8
// 440.670 us; speedup vs baseline: 1.1853x; 1.0304x over previous
//
#include <hip/hip_runtime.h>

// ---------------------------------------------------------------------------
// GCN encoder (4 conv layers, shared CSR graph) + 3-layer MLP decoder.
// Round 8: agg quarter-per-node (no fold, no masks via zero-row, packed f32
// adds); GEMM 2 row-tiles/wave (halve LDS reads + Ws staging per MFMA).
// ---------------------------------------------------------------------------

typedef __attribute__((ext_vector_type(8))) short short8;
typedef __attribute__((ext_vector_type(4))) float floatx4;
typedef __attribute__((ext_vector_type(2))) float floatx2;

#define BIN_CH 8192          // edges per bin block
#define NBMAX 512            // max buckets supported

__device__ __forceinline__ unsigned short f2bf(float f) {
    unsigned int u = __float_as_uint(f);
    u += 0x7fffu + ((u >> 16) & 1u);          // round-to-nearest-even
    return (unsigned short)(u >> 16);
}
__device__ __forceinline__ float bflo(unsigned int u) { return __uint_as_float(u << 16); }
__device__ __forceinline__ float bfhi(unsigned int u) { return __uint_as_float(u & 0xffff0000u); }
__device__ __forceinline__ unsigned char f2fp8(float f) {
    return (unsigned char)(__builtin_amdgcn_cvt_pk_fp8_f32(f, f, 0, false) & 0xFF);
}

// ---- graph build ----------------------------------------------------------

// block-aggregated binning: LDS hist -> local scan -> 1 global atomic per
// (block,bucket) run reservation -> dense run writes into bucket segments.
__global__ __launch_bounds__(512) void bin_kernel(
        const int* __restrict__ src, const int* __restrict__ dst,
        int* __restrict__ gfill, unsigned int* __restrict__ binbuf,
        int NB, int C, int E) {
    __shared__ int hist[NBMAX];
    __shared__ int start[NBMAX];
    __shared__ int dstoff[NBMAX];
    int tid = threadIdx.x;
    int e0 = blockIdx.x * BIN_CH;
    for (int i = tid; i < NB; i += 512) hist[i] = 0;
    __syncthreads();
    for (int i = tid; i < BIN_CH; i += 512) {
        int e = e0 + i;
        if (e < E) atomicAdd(&hist[dst[e] >> 9], 1);
    }
    __syncthreads();
    if (tid < 64) {                       // wave 0: exclusive scan hist->start
        int carry = 0;
        for (int base = 0; base < NB; base += 64) {
            int idx = base + tid;
            int v = (idx < NB) ? hist[idx] : 0;
            int s = v;
            #pragma unroll
            for (int off = 1; off < 64; off <<= 1) {
                int u = __shfl_up(s, off);
                if (tid >= off) s += u;
            }
            if (idx < NB) start[idx] = carry + s - v;
            carry += __shfl(s, 63);
        }
    }
    __syncthreads();
    for (int i = tid; i < NB; i += 512) { // reserve global runs
        int cnt = hist[i];
        int g = cnt ? atomicAdd(&gfill[i], cnt) : 0;
        dstoff[i] = g - start[i];
        hist[i] = start[i];               // reuse as local cursor
    }
    __syncthreads();
    for (int i = tid; i < BIN_CH; i += 512) {
        int e = e0 + i;
        if (e >= E) continue;
        int d = dst[e];
        int b = d >> 9;
        int slot = atomicAdd(&hist[b], 1);            // local rank
        int gidx = b * C + dstoff[b] + slot;
        if (gidx < (b + 1) * C)
            binbuf[gidx] = (unsigned int)src[e] | ((unsigned int)(d & 511) << 17);
    }
}

// exclusive scan over NB bucket sizes (1 wave)
__global__ void bscan_kernel(const int* __restrict__ gfill, int* __restrict__ bbase, int NB) {
    int lane = threadIdx.x;
    int carry = 0;
    for (int base = 0; base < NB; base += 64) {
        int idx = base + lane;
        int v = (idx < NB) ? gfill[idx] : 0;
        int s = v;
        #pragma unroll
        for (int off = 1; off < 64; off <<= 1) {
            int u = __shfl_up(s, off);
            if (lane >= off) s += u;
        }
        if (idx < NB) bbase[idx] = carry + s - v;
        carry += __shfl(s, 63);
    }
}

// one block per bucket: hist(512) -> scan -> rowptr/dinv -> place col
__global__ __launch_bounds__(256) void build_kernel(
        const unsigned int* __restrict__ binbuf, const int* __restrict__ gfill,
        const int* __restrict__ bbase, int* __restrict__ rowptr,
        float* __restrict__ dinv, int* __restrict__ col,
        int NB, int C, int N, int E) {
    __shared__ int h[512];
    __shared__ int hs[512];
    int b = blockIdx.x, tid = threadIdx.x;
    int cnt = gfill[b];
    const unsigned int* p = binbuf + (size_t)b * C;
    for (int i = tid; i < 512; i += 256) h[i] = 0;
    __syncthreads();
    for (int i = tid; i < cnt; i += 256) atomicAdd(&h[p[i] >> 17], 1);
    __syncthreads();
    if (tid < 64) {                       // wave 0: exclusive scan h->hs
        int carry = 0;
        for (int base = 0; base < 512; base += 64) {
            int v = h[base + tid];
            int s = v;
            #pragma unroll
            for (int off = 1; off < 64; off <<= 1) {
                int u = __shfl_up(s, off);
                if (tid >= off) s += u;
            }
            hs[base + tid] = carry + s - v;
            carry += __shfl(s, 63);
        }
    }
    __syncthreads();
    int base = bbase[b];
    for (int i = tid; i < 512; i += 256) {
        int node = b * 512 + i;
        if (node < N) {
            rowptr[node] = base + hs[i];
            dinv[node] = 1.0f / sqrtf((float)(h[i] + 1));   // +1 self loop
        }
    }
    if (b == 0 && tid == 0) rowptr[N] = E;
    __syncthreads();
    for (int i = tid; i < cnt; i += 256) {  // place (hs doubles as cursor)
        unsigned int u = p[i];
        int local = u >> 17;
        int pos = atomicAdd(&hs[local], 1);
        col[base + pos] = (int)(u & 0x1FFFFu);
    }
}

// ---- weight pre-pack into MFMA B-fragment order ---------------------------

__global__ void pack_kernel(const float* __restrict__ W0, const float* __restrict__ W1,
                            const float* __restrict__ W2, const float* __restrict__ W3,
                            unsigned short* __restrict__ P0, unsigned short* __restrict__ P1,
                            unsigned short* __restrict__ P2, unsigned short* __restrict__ P3) {
    int which = blockIdx.x >> 3;
    const float* W = which == 0 ? W0 : which == 1 ? W1 : which == 2 ? W2 : W3;
    unsigned short* P = which == 0 ? P0 : which == 1 ? P1 : which == 2 ? P2 : P3;
    int f = (blockIdx.x & 7) * 256 + threadIdx.x;   // fragment id 0..2047
    int lane = f & 63, nt = (f >> 6) & 7, kc = f >> 9;
    int kbase = kc * 32 + (lane >> 4) * 8;
    int ncol = nt * 16 + (lane & 15);
    short8 frag;
    #pragma unroll
    for (int j = 0; j < 8; ++j)
        frag[j] = (short)f2bf(W[(size_t)(kbase + j) * 128 + ncol]);
    *((short8*)(P + (size_t)f * 8)) = frag;
}

// ---- input layer: t' = fp8( dinv_i * (x @ W_s) )  (N x 3 @ 3 x 128) -------

__global__ void in_gemm_kernel(const float* __restrict__ x, const float* __restrict__ W,
                               const float* __restrict__ dinv,
                               unsigned char* __restrict__ t8, int n) {
    int g = blockIdx.x * 256 + threadIdx.x;
    int i = g >> 6, c2 = g & 63;
    if (i >= n) return;
    float x0 = x[i * 3], x1 = x[i * 3 + 1], x2 = x[i * 3 + 2];
    float d = dinv[i];
    int c = c2 * 2;
    float v0 = d * (x0 * W[c]     + x1 * W[128 + c]     + x2 * W[256 + c]);
    float v1 = d * (x0 * W[c + 1] + x1 * W[128 + c + 1] + x2 * W[256 + c + 1]);
    unsigned int pk = __builtin_amdgcn_cvt_pk_fp8_f32(v0, v1, 0, false);
    ((unsigned short*)t8)[(size_t)i * 64 + c2] = (unsigned short)(pk & 0xFFFF);
}

// ---- aggregation: out_i = relu( d_i * (t'_i + sum_j t'_j) + b ) -----------
// Quarter-per-node: 16 lanes own one node's 128 B fp8 row (uint2/lane),
// 4 nodes per wave. Out-of-range slots index zero-row n (no masking).
// No cross-lane fold; packed f32 accumulate.

__global__ __launch_bounds__(256) void agg_kernel(
        const unsigned char* __restrict__ t8, const int* __restrict__ rowptr,
        const int* __restrict__ col, const float* __restrict__ dinv,
        const float* __restrict__ bias, unsigned short* __restrict__ out, int n) {
    int node = blockIdx.x * 16 + (threadIdx.x >> 4);
    int lane = threadIdx.x & 63;
    int q16 = lane >> 4;            // quarter within wave
    int lq  = lane & 15;            // 8-byte chunk within row
    if (node >= n) node = n - 1;    // dup work in tail, benign
    floatx2 acc[4];
    #pragma unroll
    for (int i = 0; i < 4; ++i) acc[i] = (floatx2){0.f, 0.f};

    int beg = rowptr[node];
    int deg = rowptr[node + 1] - beg;
    for (int base = 0; base < deg; base += 16) {
        int m = deg - base;
        int jv = (lq < m) ? col[beg + base + lq] : n;   // n = zero row
        #pragma unroll
        for (int eh = 0; eh < 2; ++eh) {
            uint2 v[8];
            #pragma unroll
            for (int q = 0; q < 8; ++q) {
                int j = __shfl(jv, q16 * 16 + eh * 8 + q);
                v[q] = ((const uint2*)(t8 + (size_t)j * 128))[lq];
            }
            #pragma unroll
            for (int q = 0; q < 8; ++q) {
                acc[0] += __builtin_amdgcn_cvt_pk_f32_fp8(v[q].x, false);
                acc[1] += __builtin_amdgcn_cvt_pk_f32_fp8(v[q].x, true);
                acc[2] += __builtin_amdgcn_cvt_pk_f32_fp8(v[q].y, false);
                acc[3] += __builtin_amdgcn_cvt_pk_f32_fp8(v[q].y, true);
            }
        }
    }
    // self term
    uint2 s = ((const uint2*)(t8 + (size_t)node * 128))[lq];
    acc[0] += __builtin_amdgcn_cvt_pk_f32_fp8(s.x, false);
    acc[1] += __builtin_amdgcn_cvt_pk_f32_fp8(s.x, true);
    acc[2] += __builtin_amdgcn_cvt_pk_f32_fp8(s.y, false);
    acc[3] += __builtin_amdgcn_cvt_pk_f32_fp8(s.y, true);

    float di = dinv[node];
    const float4* b4 = (const float4*)bias;
    float4 b0 = b4[lq * 2], b1 = b4[lq * 2 + 1];
    float o0 = fmaxf(di * acc[0].x + b0.x, 0.f), o1 = fmaxf(di * acc[0].y + b0.y, 0.f);
    float o2 = fmaxf(di * acc[1].x + b0.z, 0.f), o3 = fmaxf(di * acc[1].y + b0.w, 0.f);
    float o4 = fmaxf(di * acc[2].x + b1.x, 0.f), o5 = fmaxf(di * acc[2].y + b1.y, 0.f);
    float o6 = fmaxf(di * acc[3].x + b1.z, 0.f), o7 = fmaxf(di * acc[3].y + b1.w, 0.f);
    uint4 o;
    o.x = (unsigned int)f2bf(o0) | ((unsigned int)f2bf(o1) << 16);
    o.y = (unsigned int)f2bf(o2) | ((unsigned int)f2bf(o3) << 16);
    o.z = (unsigned int)f2bf(o4) | ((unsigned int)f2bf(o5) << 16);
    o.w = (unsigned int)f2bf(o6) | ((unsigned int)f2bf(o7) << 16);
    ((uint4*)(out + (size_t)node * 128))[lq] = o;
}

// ---- dense 128x128 GEMM via MFMA 16x16x32 bf16 ----------------------------
// 2 row-tiles per wave (32 rows): each LDS B-fragment read feeds 2 MFMAs.
// ENC: out = fp8( dinv[row] * (A@W) )   (encoder, feeds next agg gather)
// !ENC: out = bf16( relu(A@W + bias) )  (decoder)

template <bool ENC>
__global__ __launch_bounds__(256) void gemm_mfma_kernel(
        const unsigned short* __restrict__ A, const unsigned short* __restrict__ Wp,
        const float* __restrict__ bias, const float* __restrict__ dinv,
        void* __restrict__ outp, int n) {
    __shared__ unsigned short Ws[16384];   // 32 KB packed weights
    int tid = threadIdx.x;
    {
        const int4* s = (const int4*)Wp;
        int4* d = (int4*)Ws;
        #pragma unroll
        for (int i = 0; i < 8; ++i) d[tid + 256 * i] = s[tid + 256 * i];
    }
    int wave = tid >> 6, lane = tid & 63;
    int quad = lane >> 4, mrow = lane & 15;
    int row0 = blockIdx.x * 128 + wave * 32;
    __syncthreads();

    short8 af[2][4];
    #pragma unroll
    for (int t = 0; t < 2; ++t) {
        int arow = row0 + t * 16 + mrow; if (arow >= n) arow = n - 1;
        const unsigned short* abase = A + (size_t)arow * 128 + quad * 8;
        #pragma unroll
        for (int kc = 0; kc < 4; ++kc)
            af[t][kc] = *((const short8*)(abase + kc * 32));
    }

    floatx4 acc[2][8];
    #pragma unroll
    for (int t = 0; t < 2; ++t)
        #pragma unroll
        for (int nt = 0; nt < 8; ++nt) acc[t][nt] = (floatx4){0.f, 0.f, 0.f, 0.f};

    #pragma unroll
    for (int kc = 0; kc < 4; ++kc) {
        #pragma unroll
        for (int nt = 0; nt < 8; ++nt) {
            short8 bf = *((const short8*)(Ws + ((kc * 8 + nt) * 64 + lane) * 8));
            acc[0][nt] = __builtin_amdgcn_mfma_f32_16x16x32_bf16(af[0][kc], bf, acc[0][nt], 0, 0, 0);
            acc[1][nt] = __builtin_amdgcn_mfma_f32_16x16x32_bf16(af[1][kc], bf, acc[1][nt], 0, 0, 0);
        }
    }

    #pragma unroll
    for (int t = 0; t < 2; ++t) {
        int rbase = row0 + t * 16 + quad * 4;
        float dv[4];
        if (ENC) {
            #pragma unroll
            for (int r = 0; r < 4; ++r)
                dv[r] = (rbase + r < n) ? dinv[rbase + r] : 0.f;
        }
        #pragma unroll
        for (int nt = 0; nt < 8; ++nt) {
            int colc = nt * 16 + mrow;
            float bcol = ENC ? 0.f : bias[colc];
            #pragma unroll
            for (int r = 0; r < 4; ++r) {
                int row = rbase + r;
                if (row < n) {
                    float v = acc[t][nt][r];
                    if (ENC) {
                        v *= dv[r];
                        ((unsigned char*)outp)[(size_t)row * 128 + colc] = f2fp8(v);
                    } else {
                        v = fmaxf(v + bcol, 0.f);
                        ((unsigned short*)outp)[(size_t)row * 128 + colc] = f2bf(v);
                    }
                }
            }
        }
    }
}

// ---- output layer: out = h @ W_ed + b_ed + x  (128 -> 3) ------------------

__global__ __launch_bounds__(256) void out_kernel(
        const unsigned short* __restrict__ h, const float* __restrict__ W,
        const float* __restrict__ bias, const float* __restrict__ x,
        float* __restrict__ out, int n) {
    int node = blockIdx.x * 4 + (threadIdx.x >> 6);
    int lane = threadIdx.x & 63;
    if (node >= n) return;
    unsigned int hv = ((const unsigned int*)(h + (size_t)node * 128))[lane];
    float h0 = bflo(hv), h1 = bfhi(hv);
    int c = lane * 2;
    float s0 = h0 * W[c * 3]     + h1 * W[(c + 1) * 3];
    float s1 = h0 * W[c * 3 + 1] + h1 * W[(c + 1) * 3 + 1];
    float s2 = h0 * W[c * 3 + 2] + h1 * W[(c + 1) * 3 + 2];
    #pragma unroll
    for (int off = 32; off > 0; off >>= 1) {
        s0 += __shfl_down(s0, off);
        s1 += __shfl_down(s1, off);
        s2 += __shfl_down(s2, off);
    }
    if (lane == 0) {
        out[node * 3 + 0] = s0 + bias[0] + x[node * 3 + 0];
        out[node * 3 + 1] = s1 + bias[1] + x[node * 3 + 1];
        out[node * 3 + 2] = s2 + bias[2] + x[node * 3 + 2];
    }
}

// ---------------------------------------------------------------------------

extern "C" void kernel_launch(void* const* d_in, const int* in_sizes, int n_in,
                              void* d_out, int out_size, void* d_ws, size_t ws_size,
                              hipStream_t stream) {
    const float* x    = (const float*)d_in[0];
    const int*   ei   = (const int*)d_in[1];
    const float* W_s  = (const float*)d_in[2];
    const float* b_s  = (const float*)d_in[3];
    const float* W_m  = (const float*)d_in[4];
    const float* b_m  = (const float*)d_in[5];
    const float* W_e  = (const float*)d_in[6];
    const float* b_e  = (const float*)d_in[7];
    const float* W_sd = (const float*)d_in[8];
    const float* b_sd = (const float*)d_in[9];
    const float* W_md = (const float*)d_in[10];
    const float* b_md = (const float*)d_in[11];
    const float* W_ed = (const float*)d_in[12];
    const float* b_ed = (const float*)d_in[13];
    float* outp = (float*)d_out;

    const int N = in_sizes[0] / 3;
    const int E = in_sizes[1] / 2;
    const int* src = ei;
    const int* dst = ei + E;

    const int NB = (N + 511) >> 9;                 // 512-node buckets
    const int C  = (((E / NB) * 3 / 2) + 255) & ~255;   // segment cap, 1.5x mean

    char* p = (char*)d_ws;
    auto carve = [&](size_t bytes) {
        void* r = (void*)p;
        p += (bytes + 255) & ~(size_t)255;
        return r;
    };
    int*   rowptr = (int*)  carve((size_t)(N + 1) * 4);
    int*   col    = (int*)  carve((size_t)E * 4);
    float* dinv   = (float*)carve((size_t)N * 4);
    int*   gfill  = (int*)  carve((size_t)NB * 4);
    int*   bbase  = (int*)  carve((size_t)NB * 4);
    unsigned int* binbuf = (unsigned int*)carve((size_t)NB * C * 4);
    unsigned short* Wp_m  = (unsigned short*)carve(16384 * 2);
    unsigned short* Wp_e  = (unsigned short*)carve(16384 * 2);
    unsigned short* Wp_sd = (unsigned short*)carve(16384 * 2);
    unsigned short* Wp_md = (unsigned short*)carve(16384 * 2);
    unsigned char*  T8 = (unsigned char*) carve((size_t)(N + 1) * 128);   // +1 zero row
    unsigned short* A  = (unsigned short*)carve((size_t)N * 128 * 2);
    unsigned short* Bm = (unsigned short*)carve((size_t)N * 128 * 2);
    (void)ws_size;

    const int gBin = (E + BIN_CH - 1) / BIN_CH;
    const int gNode4 = (N + 3) / 4;
    const int gNode16 = (N + 15) / 16;
    const int gRow128 = (N + 127) / 128;

    // graph build
    hipMemsetAsync(gfill, 0, (size_t)NB * 4, stream);
    hipMemsetAsync(T8 + (size_t)N * 128, 0, 128, stream);   // zero row
    bin_kernel<<<gBin, 512, 0, stream>>>(src, dst, gfill, binbuf, NB, C, E);
    bscan_kernel<<<1, 64, 0, stream>>>(gfill, bbase, NB);
    build_kernel<<<NB, 256, 0, stream>>>(binbuf, gfill, bbase, rowptr, dinv, col, NB, C, N, E);

    // weight packs
    pack_kernel<<<32, 256, 0, stream>>>(W_m, W_e, W_sd, W_md, Wp_m, Wp_e, Wp_sd, Wp_md);

    // encoder (t' in fp8, h in bf16)
    in_gemm_kernel<<<(N * 64 + 255) / 256, 256, 0, stream>>>(x, W_s, dinv, T8, N);
    agg_kernel<<<gNode16, 256, 0, stream>>>(T8, rowptr, col, dinv, b_s, A, N);

    gemm_mfma_kernel<true><<<gRow128, 256, 0, stream>>>(A, Wp_m, nullptr, dinv, T8, N);
    agg_kernel<<<gNode16, 256, 0, stream>>>(T8, rowptr, col, dinv, b_m, A, N);

    gemm_mfma_kernel<true><<<gRow128, 256, 0, stream>>>(A, Wp_m, nullptr, dinv, T8, N);
    agg_kernel<<<gNode16, 256, 0, stream>>>(T8, rowptr, col, dinv, b_m, A, N);

    gemm_mfma_kernel<true><<<gRow128, 256, 0, stream>>>(A, Wp_e, nullptr, dinv, T8, N);
    agg_kernel<<<gNode16, 256, 0, stream>>>(T8, rowptr, col, dinv, b_e, A, N);

    // decoder (bf16 throughout)
    gemm_mfma_kernel<false><<<gRow128, 256, 0, stream>>>(A, Wp_sd, b_sd, nullptr, Bm, N);
    gemm_mfma_kernel<false><<<gRow128, 256, 0, stream>>>(Bm, Wp_md, b_md, nullptr, A, N);
    gemm_mfma_kernel<false><<<gRow128, 256, 0, stream>>>(A, Wp_md, b_md, nullptr, Bm, N);
    out_kernel<<<gNode4, 256, 0, stream>>>(Bm, W_ed, b_ed, x, outp, N);
}